// Round 19
// baseline (68.239 us; speedup 1.0000x reference)
//
#include <hip/hip_runtime.h>

#define IMG_H 1080
#define IMG_W 1920
#define CH 3

typedef float f32x2 __attribute__((ext_vector_type(2)));

#if __has_builtin(__builtin_elementwise_fma)
#define FMA2(a, b, c) __builtin_elementwise_fma((a), (b), (c))
#else
#define FMA2(a, b, c) ((a) * (b) + (c))
#endif

// DPP wave shifts: single VALU op, no DS pipe, no lgkmcnt (validated R14).
__device__ __forceinline__ float dpp_up1(float x) {
    int i = __float_as_int(x);
    return __int_as_float(__builtin_amdgcn_update_dpp(i, i, 0x138, 0xF, 0xF, false));
}
__device__ __forceinline__ float dpp_dn1(float x) {
    int i = __float_as_int(x);
    return __int_as_float(__builtin_amdgcn_update_dpp(i, i, 0x130, 0xF, 0xF, false));
}

__device__ __forceinline__ int reflect_row(int r) {
    return (r < 0) ? -r : ((r >= IMG_H) ? 2 * IMG_H - 2 - r : r);
}

__global__ __launch_bounds__(128)
void dssim_l1_kernel(const float* __restrict__ pred,
                     const float* __restrict__ gt,
                     float* __restrict__ out) {
    constexpr float K1 = 81.0f * 0.0001f;        // 81*C1
    constexpr float K2 = 81.0f * 0.0009f;        // 81*C2

    const f32x2 k1_ = K1, k2_ = K2;
    const f32x2 two_ = 2.0f, m2_ = -2.0f, e18_ = 18.0f, n9_ = 9.0f;
    const f32x2 mh_ = -0.5f, h_ = 0.5f, zero_ = 0.0f, one_ = 1.0f;
    const f32x2 a3_ = 0.85f / 3.0f, b3_ = 0.15f / 3.0f;

    const int lane  = threadIdx.x;                   // 0..63
    const int ty    = threadIdx.y;                   // 0..1
    const int b     = blockIdx.z;
    const int c0    = blockIdx.x * 128 + 2 * lane;   // 2 cols per stream
    const int rbase = blockIdx.y * 8 + ty * 2;
    const int r0a   = rbase;                         // stream A: out rows r0a, r0a+1
    const int r0b   = rbase + 4;                     // stream B: out rows r0b, r0b+1

    const bool l0 = (lane == 0), l63 = (lane == 63);
    const bool limg = l0  && (blockIdx.x == 0);
    const bool rimg = l63 && (blockIdx.x == 14);
    const int  hcol = l0 ? max(c0 - 1, 0) : min(c0 + 2, IMG_W - 1);
    const unsigned hbase = (unsigned)(hcol - c0);
    const bool is_edge = l0 || l63;

    const size_t img = (size_t)IMG_H * IMG_W;
    const float* __restrict__ pb[2 * CH] = {
        pred + (size_t)b * CH * img,
        pred + (size_t)b * CH * img + img,
        pred + (size_t)b * CH * img + 2 * img,
        gt   + (size_t)b * CH * img,
        gt   + (size_t)b * CH * img + img,
        gt   + (size_t)b * CH * img + 2 * img };

    // ---- row offsets for both streams ----
    unsigned off_a[4], off_b[4];
    {
        const int ra0 = reflect_row(r0a - 1);
        const int ra3 = reflect_row(r0a + 2);
        const int rb3 = reflect_row(r0b + 2);
        off_a[0] = (unsigned)ra0 * IMG_W + (unsigned)c0;
        off_a[1] = (unsigned)r0a * IMG_W + (unsigned)c0;
        off_a[2] = (unsigned)(r0a + 1) * IMG_W + (unsigned)c0;
        off_a[3] = (unsigned)ra3 * IMG_W + (unsigned)c0;
        off_b[0] = (unsigned)(r0b - 1) * IMG_W + (unsigned)c0;
        off_b[1] = (unsigned)r0b * IMG_W + (unsigned)c0;
        off_b[2] = (unsigned)(r0b + 1) * IMG_W + (unsigned)c0;
        off_b[3] = (unsigned)rb3 * IMG_W + (unsigned)c0;
    }

    // ---- halo loads first (R11 lesson), both streams ----
    float hx_a[4][CH], hy_a[4][CH], hx_b[4][CH], hy_b[4][CH];
    if (is_edge) {
#pragma unroll
        for (int i = 0; i < 4; ++i) {
            const unsigned ha = off_a[i] + hbase;
            const unsigned hb = off_b[i] + hbase;
#pragma unroll
            for (int c = 0; c < CH; ++c) {
                hx_a[i][c] = pb[c][ha];
                hy_a[i][c] = pb[CH + c][ha];
                hx_b[i][c] = pb[c][hb];
                hy_b[i][c] = pb[CH + c][hb];
            }
        }
    }

    // ---- main loads: stream A then stream B (B stays in flight over A's consume) ----
    f32x2 qx_a[4][CH], qy_a[4][CH], qx_b[4][CH], qy_b[4][CH];
#pragma unroll
    for (int i = 0; i < 4; ++i) {
#pragma unroll
        for (int c = 0; c < CH; ++c) {
            qx_a[i][c] = *reinterpret_cast<const f32x2*>(pb[c]      + off_a[i]);
            qy_a[i][c] = *reinterpret_cast<const f32x2*>(pb[CH + c] + off_a[i]);
        }
    }
#pragma unroll
    for (int i = 0; i < 4; ++i) {
#pragma unroll
        for (int c = 0; c < CH; ++c) {
            qx_b[i][c] = *reinterpret_cast<const f32x2*>(pb[c]      + off_b[i]);
            qy_b[i][c] = *reinterpret_cast<const f32x2*>(pb[CH + c] + off_b[i]);
        }
    }

#define CONSUME(S, I, DOA, FIRSTA, DOB, FIRSTB)                             \
    _Pragma("unroll")                                                       \
    for (int c = 0; c < CH; ++c) {                                          \
        const f32x2 qxv = qx_##S[I][c], qyv = qy_##S[I][c];                 \
        float xm = dpp_up1(qxv.y), ym = dpp_up1(qyv.y);                     \
        float xp = dpp_dn1(qxv.x), yp = dpp_dn1(qyv.x);                     \
        if (l0)   { xm = hx_##S[I][c]; ym = hy_##S[I][c]; }                 \
        if (l63)  { xp = hx_##S[I][c]; yp = hy_##S[I][c]; }                 \
        if (limg) { xm = qxv.y; ym = qyv.y; }      /* reflect(-1)=1 */      \
        if (rimg) { xp = qxv.x; yp = qyv.x; }      /* reflect(1920)=1918 */ \
        const f32x2 X0 = { xm, qxv.x }, X2 = { qxv.y, xp };                 \
        const f32x2 Y0 = { ym, qyv.x }, Y2 = { qyv.y, yp };                 \
        const f32x2 WX = X0 + qxv + X2;                                     \
        const f32x2 WY = Y0 + qyv + Y2;                                     \
        const f32x2 WP = FMA2(X2, Y2, FMA2(qxv, qyv, X0 * Y0));             \
        const f32x2 WW = FMA2(X2, X2, FMA2(Y2, Y2, FMA2(qxv, qxv,           \
                         FMA2(qyv, qyv, FMA2(X0, X0, Y0 * Y0)))));          \
        if (DOA) {                                                          \
            if (FIRSTA) { Ax[c] = WX; Ay[c] = WY; Aw[c] = WW; Ap[c] = WP; } \
            else        { Ax[c] += WX; Ay[c] += WY;                         \
                          Aw[c] += WW; Ap[c] += WP; }                       \
        }                                                                   \
        if (DOB) {                                                          \
            if (FIRSTB) { Bx[c] = WX; By[c] = WY; Bw[c] = WW; Bp[c] = WP; } \
            else        { Bx[c] += WX; By[c] += WY;                         \
                          Bw[c] += WW; Bp[c] += WP; }                       \
        }                                                                   \
    }

#define SSIM2(AX, AY, AW, AP, ACC)                                          \
    {                                                                       \
        const f32x2 u  = (AX) * (AY);                                       \
        const f32x2 v  = FMA2((AY), (AY), (AX) * (AX));                     \
        const f32x2 n1 = FMA2(two_, u, k1_);                                \
        const f32x2 n2 = FMA2(e18_, (AP), FMA2(m2_, u, k2_));               \
        const f32x2 d1 = v + k1_;                                           \
        const f32x2 d2 = FMA2(n9_, (AW), k2_) - v;                          \
        const f32x2 nd = n1 * n2, dd = d1 * d2;                             \
        f32x2 rc;                                                           \
        rc.x = __builtin_amdgcn_rcpf(dd.x);                                 \
        rc.y = __builtin_amdgcn_rcpf(dd.y);                                 \
        f32x2 s = FMA2(mh_, nd * rc, h_);                                   \
        s = __builtin_elementwise_min(                                      \
                __builtin_elementwise_max(s, zero_), one_);                 \
        ACC = FMA2(a3_, s, ACC);                                            \
    }

    // process one stream: consume 4 rows, L1, SSIM, store
#define STREAM_BODY(S, R0)                                                  \
    {                                                                       \
        f32x2 Ax[CH], Ay[CH], Aw[CH], Ap[CH];                               \
        f32x2 Bx[CH], By[CH], Bw[CH], Bp[CH];                               \
        CONSUME(S, 0, true, true,  false, false)                            \
        CONSUME(S, 1, true, false, true,  true)                             \
        CONSUME(S, 2, true, false, true,  false)                            \
        CONSUME(S, 3, false, false, true, false)                            \
        f32x2 l1r0 = zero_, l1r1 = zero_;                                   \
        _Pragma("unroll")                                                   \
        for (int c = 0; c < CH; ++c) {                                      \
            f32x2 d0 = qx_##S[1][c] - qy_##S[1][c];                         \
            f32x2 d1 = qx_##S[2][c] - qy_##S[2][c];                         \
            d0.x = fabsf(d0.x); d0.y = fabsf(d0.y);                         \
            d1.x = fabsf(d1.x); d1.y = fabsf(d1.y);                         \
            l1r0 += d0; l1r1 += d1;                                         \
        }                                                                   \
        f32x2 o0 = b3_ * l1r0;                                              \
        f32x2 o1 = b3_ * l1r1;                                              \
        _Pragma("unroll")                                                   \
        for (int c = 0; c < CH; ++c) {                                      \
            SSIM2(Ax[c], Ay[c], Aw[c], Ap[c], o0)                           \
            SSIM2(Bx[c], By[c], Bw[c], Bp[c], o1)                           \
        }                                                                   \
        float* op = out + ((size_t)b * IMG_H + (R0)) * IMG_W + c0;          \
        *reinterpret_cast<f32x2*>(op) = o0;                                 \
        *reinterpret_cast<f32x2*>(op + IMG_W) = o1;                         \
    }

    STREAM_BODY(a, r0a)
    STREAM_BODY(b, r0b)

#undef STREAM_BODY
#undef SSIM2
#undef CONSUME
}

extern "C" void kernel_launch(void* const* d_in, const int* in_sizes, int n_in,
                              void* d_out, int out_size, void* d_ws, size_t ws_size,
                              hipStream_t stream) {
    const float* pred = (const float*)d_in[0];
    const float* gt   = (const float*)d_in[1];
    float* out = (float*)d_out;

    dim3 block(64, 2, 1);
    dim3 grid(IMG_W / 128, IMG_H / 8, 4);   // 15 x 135 x 4
    dssim_l1_kernel<<<grid, block, 0, stream>>>(pred, gt, out);
}

// Round 20
// 57.784 us; speedup vs baseline: 1.1809x; 1.1809x over previous
//
#include <hip/hip_runtime.h>

#define IMG_H 1080
#define IMG_W 1920
#define CH 3

typedef float f32x2 __attribute__((ext_vector_type(2)));

#if __has_builtin(__builtin_elementwise_fma)
#define FMA2(a, b, c) __builtin_elementwise_fma((a), (b), (c))
#else
#define FMA2(a, b, c) ((a) * (b) + (c))
#endif

// DPP wave shifts: single VALU op, no DS pipe, no lgkmcnt (validated R14).
__device__ __forceinline__ float dpp_up1(float x) {
    int i = __float_as_int(x);
    return __int_as_float(__builtin_amdgcn_update_dpp(i, i, 0x138, 0xF, 0xF, false));
}
__device__ __forceinline__ float dpp_dn1(float x) {
    int i = __float_as_int(x);
    return __int_as_float(__builtin_amdgcn_update_dpp(i, i, 0x130, 0xF, 0xF, false));
}

__global__ __launch_bounds__(256)
void dssim_l1_kernel(const float* __restrict__ pred,
                     const float* __restrict__ gt,
                     float* __restrict__ out) {
    constexpr float K1 = 81.0f * 0.0001f;        // 81*C1
    constexpr float K2 = 81.0f * 0.0009f;        // 81*C2

    const f32x2 k1_ = K1, k2_ = K2;
    const f32x2 two_ = 2.0f, m2_ = -2.0f, e18_ = 18.0f, n9_ = 9.0f;
    const f32x2 mh_ = -0.5f, h_ = 0.5f, zero_ = 0.0f, one_ = 1.0f;
    const f32x2 a3_ = 0.85f / 3.0f, b3_ = 0.15f / 3.0f;

    const int lane = threadIdx.x;                               // 0..63
    const int r0   = (blockIdx.y * 4 + threadIdx.y) * 2;        // even output row
    const int b    = blockIdx.z;
    const int c0   = blockIdx.x * 128 + 2 * lane;               // 2 output cols

    // input rows r0-1 .. r0+2 with reflection
    const int rws[4] = { (r0 == 0) ? 1 : r0 - 1,
                         r0, r0 + 1,
                         (r0 + 2 == IMG_H) ? IMG_H - 2 : r0 + 2 };

    const bool l0 = (lane == 0), l63 = (lane == 63);
    const bool limg = l0  && (blockIdx.x == 0);    // image left edge lane
    const bool rimg = l63 && (blockIdx.x == 14);   // image right edge lane
    const int  hcol = l0 ? max(c0 - 1, 0) : min(c0 + 2, IMG_W - 1);
    const bool is_edge = l0 || l63;

    const size_t img = (size_t)IMG_H * IMG_W;
    const float* __restrict__ pb[2 * CH] = {
        pred + (size_t)b * CH * img,
        pred + (size_t)b * CH * img + img,
        pred + (size_t)b * CH * img + 2 * img,
        gt   + (size_t)b * CH * img,
        gt   + (size_t)b * CH * img + img,
        gt   + (size_t)b * CH * img + 2 * img };

    // shared 32-bit voffsets (one per input row, reused across all 6 planes)
    unsigned off[4];
#pragma unroll
    for (int i = 0; i < 4; ++i) off[i] = (unsigned)rws[i] * IMG_W + (unsigned)c0;

    // ---- halo loads first (R11 lesson: last-issued halo forces full drain) ----
    float hx[4][CH], hy[4][CH];
    if (is_edge) {
        const unsigned hbase = (unsigned)hcol - (unsigned)c0;  // constant delta
#pragma unroll
        for (int i = 0; i < 4; ++i) {
            const unsigned ho = off[i] + hbase;
#pragma unroll
            for (int c = 0; c < CH; ++c) {
                hx[i][c] = pb[c][ho];
                hy[i][c] = pb[CH + c][ho];
            }
        }
    }

    // ---- main 24 packed-pair loads ----
    f32x2 qx[4][CH], qy[4][CH];
#pragma unroll
    for (int i = 0; i < 4; ++i) {
#pragma unroll
        for (int c = 0; c < CH; ++c) {
            qx[i][c] = *reinterpret_cast<const f32x2*>(pb[c]      + off[i]);
            qy[i][c] = *reinterpret_cast<const f32x2*>(pb[CH + c] + off[i]);
        }
    }

    // window accumulators, packed over the 2 output columns
    f32x2 Ax[CH], Ay[CH], Aw[CH], Ap[CH];   // rows -1,0,1 -> out r0
    f32x2 Bx[CH], By[CH], Bw[CH], Bp[CH];   // rows 0,1,2  -> out r0+1

#define CONSUME(I, DOA, FIRSTA, DOB, FIRSTB)                                \
    _Pragma("unroll")                                                       \
    for (int c = 0; c < CH; ++c) {                                          \
        const f32x2 qxv = qx[I][c], qyv = qy[I][c];                         \
        float xm = dpp_up1(qxv.y), ym = dpp_up1(qyv.y);                     \
        float xp = dpp_dn1(qxv.x), yp = dpp_dn1(qyv.x);                     \
        if (l0)   { xm = hx[I][c]; ym = hy[I][c]; }                         \
        if (l63)  { xp = hx[I][c]; yp = hy[I][c]; }                         \
        if (limg) { xm = qxv.y; ym = qyv.y; }      /* reflect(-1)=1 */      \
        if (rimg) { xp = qxv.x; yp = qyv.x; }      /* reflect(1920)=1918 */ \
        const f32x2 X0 = { xm, qxv.x }, X2 = { qxv.y, xp };                 \
        const f32x2 Y0 = { ym, qyv.x }, Y2 = { qyv.y, yp };                 \
        const f32x2 WX = X0 + qxv + X2;                                     \
        const f32x2 WY = Y0 + qyv + Y2;                                     \
        const f32x2 WP = FMA2(X2, Y2, FMA2(qxv, qyv, X0 * Y0));             \
        const f32x2 WW = FMA2(X2, X2, FMA2(Y2, Y2, FMA2(qxv, qxv,           \
                         FMA2(qyv, qyv, FMA2(X0, X0, Y0 * Y0)))));          \
        if (DOA) {                                                          \
            if (FIRSTA) { Ax[c] = WX; Ay[c] = WY; Aw[c] = WW; Ap[c] = WP; } \
            else        { Ax[c] += WX; Ay[c] += WY;                         \
                          Aw[c] += WW; Ap[c] += WP; }                       \
        }                                                                   \
        if (DOB) {                                                          \
            if (FIRSTB) { Bx[c] = WX; By[c] = WY; Bw[c] = WW; Bp[c] = WP; } \
            else        { Bx[c] += WX; By[c] += WY;                         \
                          Bw[c] += WW; Bp[c] += WP; }                       \
        }                                                                   \
    }

    CONSUME(0, true, true,  false, false)   // row r0-1 -> A
    CONSUME(1, true, false, true,  true)    // row r0   -> A, B
    CONSUME(2, true, false, true,  false)   // row r0+1 -> A, B
    CONSUME(3, false, false, true, false)   // row r0+2 -> B
#undef CONSUME

    // L1 terms from raw center rows (row idx 1 -> out r0, idx 2 -> out r0+1)
    f32x2 l1r0 = zero_, l1r1 = zero_;
#pragma unroll
    for (int c = 0; c < CH; ++c) {
#if __has_builtin(__builtin_elementwise_abs)
        l1r0 += __builtin_elementwise_abs(qx[1][c] - qy[1][c]);
        l1r1 += __builtin_elementwise_abs(qx[2][c] - qy[2][c]);
#else
        f32x2 d0 = qx[1][c] - qy[1][c], d1 = qx[2][c] - qy[2][c];
        d0.x = fabsf(d0.x); d0.y = fabsf(d0.y);
        d1.x = fabsf(d1.x); d1.y = fabsf(d1.y);
        l1r0 += d0; l1r1 += d1;
#endif
    }

    // ---- packed SSIM epilogue (moments scaled by 81; cancels in n/d) ----
#define SSIM2(AX, AY, AW, AP, ACC)                                          \
    {                                                                       \
        const f32x2 u  = (AX) * (AY);                                       \
        const f32x2 v  = FMA2((AY), (AY), (AX) * (AX));                     \
        const f32x2 n1 = FMA2(two_, u, k1_);                                \
        const f32x2 n2 = FMA2(e18_, (AP), FMA2(m2_, u, k2_));               \
        const f32x2 d1 = v + k1_;                                           \
        const f32x2 d2 = FMA2(n9_, (AW), k2_) - v;                          \
        const f32x2 nd = n1 * n2, dd = d1 * d2;                             \
        f32x2 rc;                                                           \
        rc.x = __builtin_amdgcn_rcpf(dd.x);                                 \
        rc.y = __builtin_amdgcn_rcpf(dd.y);                                 \
        f32x2 s = FMA2(mh_, nd * rc, h_);                                   \
        s = __builtin_elementwise_min(                                      \
                __builtin_elementwise_max(s, zero_), one_);                 \
        ACC = FMA2(a3_, s, ACC);                                            \
    }

    f32x2 o0 = b3_ * l1r0;
    f32x2 o1 = b3_ * l1r1;
#pragma unroll
    for (int c = 0; c < CH; ++c) {
        SSIM2(Ax[c], Ay[c], Aw[c], Ap[c], o0)
        SSIM2(Bx[c], By[c], Bw[c], Bp[c], o1)
    }
#undef SSIM2

    float* op = out + ((size_t)b * IMG_H + r0) * IMG_W + c0;
    *reinterpret_cast<f32x2*>(op) = o0;
    *reinterpret_cast<f32x2*>(op + IMG_W) = o1;
}

extern "C" void kernel_launch(void* const* d_in, const int* in_sizes, int n_in,
                              void* d_out, int out_size, void* d_ws, size_t ws_size,
                              hipStream_t stream) {
    const float* pred = (const float*)d_in[0];
    const float* gt   = (const float*)d_in[1];
    float* out = (float*)d_out;

    dim3 block(64, 4, 1);
    dim3 grid(IMG_W / 128, IMG_H / 8, 4);   // 15 x 135 x 4
    dssim_l1_kernel<<<grid, block, 0, stream>>>(pred, gt, out);
}